// Round 1
// baseline (2165.757 us; speedup 1.0000x reference)
//
#include <hip/hip_runtime.h>

// PointNet2Refine: ball-query -> gripper transform -> 4-layer pointwise MLP -> heads.
// B=2, NUM=512, A=20000, Bn=1024, NUM_NEI=192, GRIPPER_NUM=64.

#define A_PTS   20000
#define BN_TOT  1024
#define NNEI    192
#define GNUM    64
#define R2      0.09f

// ---------------- Kernel 1: ball query, ordered first-K with padding --------
// One wave per (b,m). Scan points in index order; ballot-compact first 192
// valid indices; pad remainder with first valid index (0 if none).
__global__ __launch_bounds__(256) void k_ballq(const float* __restrict__ grasp,
                                               const float* __restrict__ pc,
                                               int* __restrict__ idx,
                                               int* __restrict__ ucnt)
{
    int wid  = blockIdx.x * 4 + (threadIdx.x >> 6);
    int lane = threadIdx.x & 63;
    if (wid >= BN_TOT) return;

    const float* g = grasp + wid * 8;
    float cx = g[0], cy = g[1], cz = g[2];
    float cc = cx*cx + cy*cy + cz*cz;
    const float* pcb = pc + (wid >> 9) * (A_PTS * 6);
    int* my = idx + wid * NNEI;

    int found = 0;
    int padval = 0;
    for (int a0 = 0; a0 < A_PTS; a0 += 64) {
        int a = a0 + lane;
        bool valid = false;
        if (a < A_PTS) {
            const float* pp = pcb + a * 6;
            float px = pp[0], py = pp[1], pz = pp[2];
            float xx = px*px + py*py + pz*pz;
            float dt = cx*px + cy*py + cz*pz;
            float d2 = cc + xx - 2.0f * dt;   // match reference formula structure
            valid = d2 < R2;
        }
        unsigned long long mb = __ballot(valid);
        if (found == 0 && mb != 0ull)
            padval = a0 + (int)__builtin_ctzll(mb);   // first valid index overall
        if (valid) {
            int pos = found + __popcll(mb & ((1ull << lane) - 1ull));
            if (pos < NNEI) my[pos] = a;
        }
        found += __popcll(mb);
        if (found >= NNEI) break;
    }
    int cnt = found < NNEI ? found : NNEI;
    for (int p = cnt + lane; p < NNEI; p += 64) my[p] = padval;
    if (lane == 0) ucnt[wid] = found;
}

// ---------------- Kernel 2: gripper transform + inside-box first-64 ---------
// One wave per bn row. All lanes redundantly build the rotation, then 3x64
// neighbors are transformed, box-tested, ballot-compacted into gpc (float4).
__global__ __launch_bounds__(256) void k_transform(const float* __restrict__ grasp,
                                                   const float* __restrict__ pc,
                                                   const int* __restrict__ idx,
                                                   const int* __restrict__ ucnt,
                                                   float4* __restrict__ gpc,
                                                   float* __restrict__ mask_out)
{
    int bn   = blockIdx.x * 4 + (threadIdx.x >> 6);
    int lane = threadIdx.x & 63;
    if (bn >= BN_TOT) return;

    const float* g = grasp + bn * 8;
    float g0=g[0], g1=g[1], g2=g[2], g3=g[3], g4=g[4], g5=g[5], g6=g[6], g7=g[7];
    float gsum = g0+g1+g2+g3+g4+g5+g6+g7;
    bool gmask = (gsum != -8.0f);

    float cx=g0, cy=g1, cz=g2;
    float ay0=g3, ay1=g4, ay2=g5;
    float cth = cosf(g6), sth = sinf(g6);

    float ny = sqrtf(ay0*ay0 + ay1*ay1 + ay2*ay2) + 1e-12f;
    ay0/=ny; ay1/=ny; ay2/=ny;
    float ax0=ay1, ax1=-ay0;                     // [y1, -y0, 0]
    float nx = sqrtf(ax0*ax0 + ax1*ax1) + 1e-12f;
    ax0/=nx; ax1/=nx;
    // az = cross(ax, ay) with ax2 == 0
    float az0 =  ax1*ay2;
    float az1 = -ax0*ay2;
    float az2 =  ax0*ay1 - ax1*ay0;
    float nz = sqrtf(az0*az0 + az1*az1 + az2*az2);
    if (nz == 0.0f) { az0=0.f; az1=0.f; az2=1.f; }
    else            { az0/=nz; az1/=nz; az2/=nz; }
    // approach = M[:,0] = c*ax + s*az, normalized
    float ap0 = ax0*cth + az0*sth;
    float ap1 = ax1*cth + az1*sth;
    float ap2 =           az2*sth;
    float na = sqrtf(ap0*ap0 + ap1*ap1 + ap2*ap2) + 1e-12f;
    ap0/=na; ap1/=na; ap2/=na;
    // minor = cross(approach, ay)
    float mi0 = ap1*ay2 - ap2*ay1;
    float mi1 = ap2*ay0 - ap0*ay2;
    float mi2 = ap0*ay1 - ap1*ay0;

    const int* my = idx + bn * NNEI;
    const float* pcb = pc + (bn >> 9) * (A_PTS * 6);
    float4* out = gpc + bn * GNUM;

    // transform of neighbor n=0 (padding value when zero inside)
    float padx, pady, padz;
    {
        int ai = my[0];
        const float* pp = pcb + ai * 6;
        float qx = pp[0]-cx, qy = pp[1]-cy, qz = pp[2]-cz;
        padx = ap0*qx + ap1*qy + ap2*qz;
        pady = ay0*qx + ay1*qy + ay2*qz;
        padz = mi0*qx + mi1*qy + mi2*qz;
    }

    int found = 0;
    for (int c0 = 0; c0 < NNEI; c0 += 64) {
        int ai = my[c0 + lane];
        const float* pp = pcb + ai * 6;
        float qx = pp[0]-cx, qy = pp[1]-cy, qz = pp[2]-cz;
        float tx = ap0*qx + ap1*qy + ap2*qz;
        float ty = ay0*qx + ay1*qy + ay2*qz;
        float tz = mi0*qx + mi1*qy + mi2*qz;
        bool inside = (tx > 0.f) && (tx < 0.3f) && (ty > -0.15f) && (ty < 0.15f)
                   && (tz > -0.1f) && (tz < 0.1f);
        unsigned long long mb = __ballot(inside);
        if (found == 0 && mb != 0ull) {          // first inside point = pad value
            int fl = (int)__builtin_ctzll(mb);
            padx = __shfl(tx, fl, 64);
            pady = __shfl(ty, fl, 64);
            padz = __shfl(tz, fl, 64);
        }
        if (inside) {
            int pos = found + __popcll(mb & ((1ull << lane) - 1ull));
            if (pos < GNUM) out[pos] = make_float4(tx, ty, tz, 0.f);
        }
        found += __popcll(mb);
        if (found >= GNUM) break;
    }
    int cnt = found < GNUM ? found : GNUM;
    for (int p = cnt + lane; p < GNUM; p += 64)
        out[p] = make_float4(padx, pady, padz, 0.f);
    if (lane == 0)
        mask_out[bn] = (ucnt[bn] > 0 && found > 0 && gmask) ? 1.0f : 0.0f;
}

// ---------------- Kernel 3: fused 4-layer MLP + heads + dc contraction ------
// One block (512 thr = 8 waves) per bn row. thread = (g = wave 0..7, n = lane
// 0..63 = gripper slot). Activations in LDS [chan][64]; weights via
// wave-uniform (readfirstlane) pointers -> scalar loads, 32 FMA per LDS read.
__global__ __launch_bounds__(512, 1) void k_mlp(const float4* __restrict__ gpc,
    const float* __restrict__ s1,
    const float* __restrict__ W1, const float* __restrict__ b1,
    const float* __restrict__ W2, const float* __restrict__ b2,
    const float* __restrict__ W3, const float* __restrict__ b3,
    const float* __restrict__ W4, const float* __restrict__ b4,
    const float* __restrict__ regw, const float* __restrict__ regb,
    const float* __restrict__ clsw, const float* __restrict__ clsb,
    const float* __restrict__ dcrw, const float* __restrict__ dcrb,
    const float* __restrict__ dccw, const float* __restrict__ dccb,
    float* __restrict__ outp)
{
    __shared__ float bufA[256][64];   // 64 KiB
    __shared__ float bufB[256][64];   // 64 KiB
    __shared__ float sdot[10];

    int bn  = blockIdx.x;
    int tid = threadIdx.x;
    int n   = tid & 63;
    int g   = __builtin_amdgcn_readfirstlane(tid >> 6);   // wave id, force SGPR

    float4 p = gpc[bn * 64 + n];

    // ---- layer 1 (3->512, two halves of 256) fused with layer 2 accumulation
    float acc2[32];
    #pragma unroll
    for (int j = 0; j < 32; ++j) acc2[j] = 0.f;

    for (int half = 0; half < 2; ++half) {
        __syncthreads();              // protect bufA from previous half's readers
        #pragma unroll
        for (int j = 0; j < 32; ++j) {
            int o = half * 256 + g * 32 + j;
            float v = W1[o*3+0]*p.x + W1[o*3+1]*p.y + W1[o*3+2]*p.z + b1[o];
            bufA[g*32 + j][n] = fmaxf(v, 0.f);
        }
        __syncthreads();
        const float* w2 = W2 + (g * 32) * 512 + half * 256;
        for (int k = 0; k < 256; ++k) {
            float hv = bufA[k][n];
            #pragma unroll
            for (int j = 0; j < 32; ++j)
                acc2[j] = fmaf(w2[j*512 + k], hv, acc2[j]);
        }
    }
    #pragma unroll
    for (int j = 0; j < 32; ++j) {
        int o = g*32 + j;
        bufB[o][n] = fmaxf(acc2[j] + b2[o], 0.f);   // h2
    }
    __syncthreads();

    // ---- layer 3 (256->256): read bufB, write bufA
    float acc3[32];
    #pragma unroll
    for (int j = 0; j < 32; ++j) acc3[j] = 0.f;
    {
        const float* w3 = W3 + (g * 32) * 256;
        for (int k = 0; k < 256; ++k) {
            float hv = bufB[k][n];
            #pragma unroll
            for (int j = 0; j < 32; ++j)
                acc3[j] = fmaf(w3[j*256 + k], hv, acc3[j]);
        }
    }
    #pragma unroll
    for (int j = 0; j < 32; ++j) {
        int o = g*32 + j;
        bufA[o][n] = fmaxf(acc3[j] + b3[o], 0.f);   // h3
    }
    __syncthreads();

    // ---- layer 4 (256->128): read bufA, write bufB[0..127]
    float acc4[16];
    #pragma unroll
    for (int j = 0; j < 16; ++j) acc4[j] = 0.f;
    {
        const float* w4 = W4 + (g * 16) * 256;
        for (int k = 0; k < 256; ++k) {
            float hv = bufA[k][n];
            #pragma unroll
            for (int j = 0; j < 16; ++j)
                acc4[j] = fmaf(w4[j*256 + k], hv, acc4[j]);
        }
    }
    #pragma unroll
    for (int j = 0; j < 16; ++j) {
        int o = g*16 + j;
        bufB[o][n] = fmaxf(acc4[j] + b4[o], 0.f);   // h4
    }
    __syncthreads();

    // ---- heads. c = 0..7 -> reg head, c = 8..9 -> cls head.
    // s1 branch is broadcast over n: one 256-dot per (bn, c), done by wave 1.
    if (g == 1 && n < 10) {
        int c = n;
        const float* w  = (c < 8) ? (regw + c * 384) : (clsw + (c - 8) * 384);
        const float* sf = s1 + bn * 256;
        float acc = 0.f;
        for (int f = 0; f < 256; ++f) acc = fmaf(w[f], sf[f], acc);
        sdot[c] = acc;
    }
    // h4 branch: wave 0, lane n owns slot n; 10 head rows over 128 channels.
    float r[10];
    if (g == 0) {
        #pragma unroll
        for (int c = 0; c < 10; ++c) r[c] = 0.f;
        for (int k = 0; k < 128; ++k) {
            float hv = bufB[k][n];
            #pragma unroll
            for (int c = 0; c < 10; ++c) {
                const float* w = (c < 8) ? (regw + c * 384) : (clsw + (c - 8) * 384);
                r[c] = fmaf(w[256 + k], hv, r[c]);
            }
        }
    }
    __syncthreads();
    // dc contraction over n (wave-wide shuffle reduce), biases, store.
    if (g == 0) {
        #pragma unroll
        for (int c = 0; c < 10; ++c) {
            float dcw, hb, db;
            if (c < 8) { dcw = dcrw[c*64 + n];     hb = regb[c];   db = dcrb[c];   }
            else       { dcw = dccw[(c-8)*64 + n]; hb = clsb[c-8]; db = dccb[c-8]; }
            float val = (r[c] + sdot[c] + hb) * dcw;
            #pragma unroll
            for (int off = 32; off >= 1; off >>= 1)
                val += __shfl_xor(val, off, 64);
            if (n == 0) {
                if (c < 8) outp[2048 + bn*8 + c] = val + db;   // x_reg
                else       outp[bn*2 + (c-8)]    = val + db;   // x_cls
            }
        }
    }
}

extern "C" void kernel_launch(void* const* d_in, const int* in_sizes, int n_in,
                              void* d_out, int out_size, void* d_ws, size_t ws_size,
                              hipStream_t stream)
{
    const float* grasp = (const float*)d_in[0];
    const float* pc    = (const float*)d_in[1];
    // d_in[2] all_feature: grouped result is unused in the reference
    const float* s1    = (const float*)d_in[3];
    const float* W1 = (const float*)d_in[4];  const float* b1 = (const float*)d_in[5];
    const float* W2 = (const float*)d_in[6];  const float* b2 = (const float*)d_in[7];
    const float* W3 = (const float*)d_in[8];  const float* b3 = (const float*)d_in[9];
    const float* W4 = (const float*)d_in[10]; const float* b4 = (const float*)d_in[11];
    const float* regw = (const float*)d_in[12]; const float* regb = (const float*)d_in[13];
    const float* clsw = (const float*)d_in[14]; const float* clsb = (const float*)d_in[15];
    const float* dcrw = (const float*)d_in[16]; const float* dcrb = (const float*)d_in[17];
    const float* dccw = (const float*)d_in[18]; const float* dccb = (const float*)d_in[19];
    float* outp = (float*)d_out;
    // out layout: x_cls [0,2048) | x_reg [2048,10240) | mask [10240,11264)

    char* ws = (char*)d_ws;
    int*    idx  = (int*)ws;                          // 1024*192*4 = 786432 B
    int*    ucnt = (int*)(ws + 786432);               // 4096 B
    float4* gpc  = (float4*)(ws + 786432 + 4096);     // 1024*64*16 = 1 MiB

    k_ballq<<<256, 256, 0, stream>>>(grasp, pc, idx, ucnt);
    k_transform<<<256, 256, 0, stream>>>(grasp, pc, idx, ucnt, gpc, outp + 10240);
    k_mlp<<<1024, 512, 0, stream>>>(gpc, s1, W1, b1, W2, b2, W3, b3, W4, b4,
                                    regw, regb, clsw, clsb, dcrw, dcrb, dccw, dccb,
                                    outp);
}

// Round 2
// 215.326 us; speedup vs baseline: 10.0581x; 10.0581x over previous
//
#include <hip/hip_runtime.h>
#include <hip/hip_bf16.h>

// PointNet2Refine: ball-query -> gripper transform -> MFMA bf16 MLP -> heads.
// B=2, NUM=512, A=20000, Bn=1024, NUM_NEI=192, GRIPPER_NUM=64.

#define A_PTS   20000
#define BN_TOT  1024
#define NNEI    192
#define GNUM    64
#define R2      0.09f
#define CHUNKS  313   // ceil(20000/64)

typedef __attribute__((ext_vector_type(8))) short bf16x8;
typedef __attribute__((ext_vector_type(4))) float f32x4;

__device__ inline unsigned short f2bf(float v) {
    __hip_bfloat16 h = __float2bfloat16(v);
    return *reinterpret_cast<unsigned short*>(&h);
}

// ---------------- Kernel 1: ball query, block-per-center, 4 waves ----------
// Phase1: ballot masks per 64-pt chunk -> LDS. Phase2: wave0 prefix-scans
// chunk popcounts (ordered). Phase3: ordered compacted emit. Phase4: pad.
__global__ __launch_bounds__(256) void k_ballq(const float* __restrict__ grasp,
                                               const float* __restrict__ pc,
                                               int* __restrict__ idx,
                                               int* __restrict__ ucnt)
{
    __shared__ unsigned long long masks[CHUNKS];
    __shared__ int off[CHUNKS];
    __shared__ int sh_total, sh_pad;

    int bn   = blockIdx.x;
    int tid  = threadIdx.x;
    int lane = tid & 63;
    int w    = tid >> 6;

    const float* g = grasp + bn * 8;
    float cx = g[0], cy = g[1], cz = g[2];
    float cc = cx*cx + cy*cy + cz*cz;
    const float* pcb = pc + (bn >> 9) * (A_PTS * 6);

    for (int c = w; c < CHUNKS; c += 4) {
        int a = c * 64 + lane;
        bool valid = false;
        if (a < A_PTS) {
            const float* pp = pcb + a * 6;
            float px = pp[0], py = pp[1], pz = pp[2];
            float xx = px*px + py*py + pz*pz;
            float dt = cx*px + cy*py + cz*pz;
            valid = (cc + xx - 2.0f * dt) < R2;   // match reference formula
        }
        unsigned long long mb = __ballot(valid);
        if (lane == 0) masks[c] = mb;
    }
    __syncthreads();

    if (w == 0) {
        int c0 = lane * 5;                     // lane owns chunks [c0, c0+5)
        int cnts[5]; int s = 0;
        #pragma unroll
        for (int i = 0; i < 5; ++i) {
            int c = c0 + i;
            int v = (c < CHUNKS) ? __popcll(masks[c]) : 0;
            cnts[i] = v; s += v;
        }
        int incl = s;
        for (int o2 = 1; o2 < 64; o2 <<= 1) {
            int v = __shfl_up(incl, o2, 64);
            if (lane >= o2) incl += v;
        }
        int run = incl - s;                    // exclusive base for this lane
        #pragma unroll
        for (int i = 0; i < 5; ++i) {
            int c = c0 + i;
            if (c < CHUNKS) off[c] = run;
            run += cnts[i];
        }
        int total = __shfl(incl, 63, 64);
        int fc = 0x7fffffff;
        #pragma unroll
        for (int i = 0; i < 5; ++i) {
            int c = c0 + i;
            if (c < CHUNKS && masks[c] != 0ull) { fc = c; break; }
        }
        for (int o2 = 32; o2 >= 1; o2 >>= 1) fc = min(fc, __shfl_xor(fc, o2, 64));
        if (lane == 0) {
            sh_total = total;
            sh_pad = (fc == 0x7fffffff) ? 0
                     : fc * 64 + (int)__builtin_ctzll(masks[fc]);
            ucnt[bn] = total;
        }
    }
    __syncthreads();

    int total = sh_total, padval = sh_pad;
    int* my = idx + bn * NNEI;
    for (int c = w; c < CHUNKS; c += 4) {
        unsigned long long mb = masks[c];
        int base = off[c];
        if (mb != 0ull && base < NNEI) {
            if ((mb >> lane) & 1ull) {
                int pos = base + __popcll(mb & ((1ull << lane) - 1ull));
                if (pos < NNEI) my[pos] = c * 64 + lane;
            }
        }
    }
    int cnt = total < NNEI ? total : NNEI;
    for (int p = cnt + tid; p < NNEI; p += 256) my[p] = padval;
}

// ---------------- Kernel 2: gripper transform + inside-box first-64 ---------
__global__ __launch_bounds__(256) void k_transform(const float* __restrict__ grasp,
                                                   const float* __restrict__ pc,
                                                   const int* __restrict__ idx,
                                                   const int* __restrict__ ucnt,
                                                   float4* __restrict__ gpc,
                                                   float* __restrict__ mask_out)
{
    int bn   = blockIdx.x * 4 + (threadIdx.x >> 6);
    int lane = threadIdx.x & 63;
    if (bn >= BN_TOT) return;

    const float* g = grasp + bn * 8;
    float g0=g[0], g1=g[1], g2=g[2], g3=g[3], g4=g[4], g5=g[5], g6=g[6], g7=g[7];
    float gsum = g0+g1+g2+g3+g4+g5+g6+g7;
    bool gmask = (gsum != -8.0f);

    float cx=g0, cy=g1, cz=g2;
    float ay0=g3, ay1=g4, ay2=g5;
    float cth = cosf(g6), sth = sinf(g6);

    float ny = sqrtf(ay0*ay0 + ay1*ay1 + ay2*ay2) + 1e-12f;
    ay0/=ny; ay1/=ny; ay2/=ny;
    float ax0=ay1, ax1=-ay0;
    float nx = sqrtf(ax0*ax0 + ax1*ax1) + 1e-12f;
    ax0/=nx; ax1/=nx;
    float az0 =  ax1*ay2;
    float az1 = -ax0*ay2;
    float az2 =  ax0*ay1 - ax1*ay0;
    float nz = sqrtf(az0*az0 + az1*az1 + az2*az2);
    if (nz == 0.0f) { az0=0.f; az1=0.f; az2=1.f; }
    else            { az0/=nz; az1/=nz; az2/=nz; }
    float ap0 = ax0*cth + az0*sth;
    float ap1 = ax1*cth + az1*sth;
    float ap2 =           az2*sth;
    float na = sqrtf(ap0*ap0 + ap1*ap1 + ap2*ap2) + 1e-12f;
    ap0/=na; ap1/=na; ap2/=na;
    float mi0 = ap1*ay2 - ap2*ay1;
    float mi1 = ap2*ay0 - ap0*ay2;
    float mi2 = ap0*ay1 - ap1*ay0;

    const int* my = idx + bn * NNEI;
    const float* pcb = pc + (bn >> 9) * (A_PTS * 6);
    float4* out = gpc + bn * GNUM;

    float padx, pady, padz;
    {
        int ai = my[0];
        const float* pp = pcb + ai * 6;
        float qx = pp[0]-cx, qy = pp[1]-cy, qz = pp[2]-cz;
        padx = ap0*qx + ap1*qy + ap2*qz;
        pady = ay0*qx + ay1*qy + ay2*qz;
        padz = mi0*qx + mi1*qy + mi2*qz;
    }

    int found = 0;
    for (int c0 = 0; c0 < NNEI; c0 += 64) {
        int ai = my[c0 + lane];
        const float* pp = pcb + ai * 6;
        float qx = pp[0]-cx, qy = pp[1]-cy, qz = pp[2]-cz;
        float tx = ap0*qx + ap1*qy + ap2*qz;
        float ty = ay0*qx + ay1*qy + ay2*qz;
        float tz = mi0*qx + mi1*qy + mi2*qz;
        bool inside = (tx > 0.f) && (tx < 0.3f) && (ty > -0.15f) && (ty < 0.15f)
                   && (tz > -0.1f) && (tz < 0.1f);
        unsigned long long mb = __ballot(inside);
        if (found == 0 && mb != 0ull) {
            int fl = (int)__builtin_ctzll(mb);
            padx = __shfl(tx, fl, 64);
            pady = __shfl(ty, fl, 64);
            padz = __shfl(tz, fl, 64);
        }
        if (inside) {
            int pos = found + __popcll(mb & ((1ull << lane) - 1ull));
            if (pos < GNUM) out[pos] = make_float4(tx, ty, tz, 0.f);
        }
        found += __popcll(mb);
        if (found >= GNUM) break;
    }
    int cnt = found < GNUM ? found : GNUM;
    for (int p = cnt + lane; p < GNUM; p += 64)
        out[p] = make_float4(padx, pady, padz, 0.f);
    if (lane == 0)
        mask_out[bn] = (ucnt[bn] > 0 && found > 0 && gmask) ? 1.0f : 0.0f;
}

// ---------------- Kernel P: pack weights to frag-linear bf16 ----------------
// A-frag layout: dst[((ot*KS + ks)*64 + lane)*8 + e] = W[ot*16+(lane&15)]
//                                                      [ks*32+(lane>>4)*8+e]
// Same k-map is used for B-frags from LDS, so any k-map error cancels.
#define NW2 131072   // 16 ot * 16 ks * 512
#define NW3 65536    // 16 ot *  8 ks * 512
#define NW4 32768    //  8 ot *  8 ks * 512
#define NHP 2048     //  1 ot *  4 ks * 512
__global__ __launch_bounds__(256) void k_pack(const float* __restrict__ W2,
                                              const float* __restrict__ W3,
                                              const float* __restrict__ W4,
                                              const float* __restrict__ regw,
                                              const float* __restrict__ clsw,
                                              unsigned short* __restrict__ W2p,
                                              unsigned short* __restrict__ W3p,
                                              unsigned short* __restrict__ W4p,
                                              unsigned short* __restrict__ Hp)
{
    int stride = gridDim.x * blockDim.x;
    for (int t = blockIdx.x * blockDim.x + threadIdx.x;
         t < NW2 + NW3 + NW4 + NHP; t += stride) {
        const float* src; unsigned short* dst; int KS, K, i;
        if (t < NW2)                   { src = W2; dst = W2p; KS = 16; K = 512; i = t; }
        else if (t < NW2+NW3)          { src = W3; dst = W3p; KS = 8;  K = 256; i = t-NW2; }
        else if (t < NW2+NW3+NW4)      { src = W4; dst = W4p; KS = 8;  K = 256; i = t-NW2-NW3; }
        else {
            int i2 = t - NW2 - NW3 - NW4;
            int ks = i2 / 512, r = i2 % 512, l = r >> 3, e = r & 7;
            int c = l & 15;
            int k = 256 + ks*32 + ((l >> 4) << 3) + e;
            float v = 0.f;
            if (c < 8)       v = regw[c*384 + k];
            else if (c < 10) v = clsw[(c-8)*384 + k];
            Hp[i2] = f2bf(v);
            continue;
        }
        int ot = i / (KS*512), rem = i % (KS*512);
        int ks = rem / 512, r = rem % 512, l = r >> 3, e = r & 7;
        int o = ot*16 + (l & 15);
        int k = ks*32 + ((l >> 4) << 3) + e;
        dst[i] = f2bf(src[o*K + k]);
    }
}

// ---------------- Kernel 3: MFMA bf16 MLP + heads + dc ----------------------
// One block = one bn row (64 points), 512 thr = 8 waves. LDS activations in
// [k>>3][p][k&7] bf16 layout (B-frag = one ds_read_b128). Wave w owns o-tiles
// {2w,2w+1} x all 4 p-tiles -> each block streams W2/W3/W4 exactly once.
__global__ __launch_bounds__(512, 4) void k_mlp(const float4* __restrict__ gpc,
    const float* __restrict__ s1,
    const float* __restrict__ W1, const float* __restrict__ b1,
    const float* __restrict__ b2, const float* __restrict__ b3,
    const float* __restrict__ b4,
    const unsigned short* __restrict__ W2p, const unsigned short* __restrict__ W3p,
    const unsigned short* __restrict__ W4p, const unsigned short* __restrict__ Hp,
    const float* __restrict__ regw, const float* __restrict__ regb,
    const float* __restrict__ clsw, const float* __restrict__ clsb,
    const float* __restrict__ dcrw, const float* __restrict__ dcrb,
    const float* __restrict__ dccw, const float* __restrict__ dccb,
    float* __restrict__ outp)
{
    __shared__ __align__(16) unsigned short bufA[32*64*8];  // 32 KiB
    __shared__ __align__(16) unsigned short bufB[32*64*8];  // 32 KiB
    __shared__ float sdot[16];
    __shared__ float pdc[4][16];

    int bn   = blockIdx.x;
    int tid  = threadIdx.x;
    int lane = tid & 63;
    int w    = tid >> 6;      // 0..7
    int kg   = lane >> 4;     // 0..3
    int lp   = lane & 15;

    const bf16x8* pA  = reinterpret_cast<const bf16x8*>(bufA);
    const bf16x8* pB  = reinterpret_cast<const bf16x8*>(bufB);
    const bf16x8* w2f = reinterpret_cast<const bf16x8*>(W2p);
    const bf16x8* w3f = reinterpret_cast<const bf16x8*>(W3p);
    const bf16x8* w4f = reinterpret_cast<const bf16x8*>(W4p);
    const bf16x8* hpf = reinterpret_cast<const bf16x8*>(Hp);

    float4 P = gpc[bn * 64 + lane];

    // ---- L1 (fp32 VALU) + L2 (MFMA, K=512 streamed in two 256 halves) ----
    f32x4 acc2[2][4];
    #pragma unroll
    for (int a = 0; a < 2; ++a)
        #pragma unroll
        for (int p = 0; p < 4; ++p) acc2[a][p] = (f32x4)0.f;

    for (int h = 0; h < 2; ++h) {
        __syncthreads();
        #pragma unroll
        for (int i = 0; i < 4; ++i) {
            int ob = w + 8*i;                 // local o-block 0..31
            unsigned int u[4];
            #pragma unroll
            for (int jj = 0; jj < 4; ++jj) {
                int o = h*256 + ob*8 + jj*2;
                float v0 = fmaxf(W1[3*o  ]*P.x + W1[3*o+1]*P.y + W1[3*o+2]*P.z + b1[o], 0.f);
                float v1 = fmaxf(W1[3*o+3]*P.x + W1[3*o+4]*P.y + W1[3*o+5]*P.z + b1[o+1], 0.f);
                u[jj] = (unsigned int)f2bf(v0) | ((unsigned int)f2bf(v1) << 16);
            }
            uint4 q = make_uint4(u[0], u[1], u[2], u[3]);
            *reinterpret_cast<uint4*>(&bufA[(ob*64 + lane)*8]) = q;
        }
        __syncthreads();
        for (int ks = 0; ks < 8; ++ks) {
            int ksg = h*8 + ks;
            bf16x8 a0 = w2f[((2*w  )*16 + ksg)*64 + lane];
            bf16x8 a1 = w2f[((2*w+1)*16 + ksg)*64 + lane];
            #pragma unroll
            for (int pt = 0; pt < 4; ++pt) {
                bf16x8 b = pA[(ks*4 + kg)*64 + pt*16 + lp];
                acc2[0][pt] = __builtin_amdgcn_mfma_f32_16x16x32_bf16(a0, b, acc2[0][pt], 0, 0, 0);
                acc2[1][pt] = __builtin_amdgcn_mfma_f32_16x16x32_bf16(a1, b, acc2[1][pt], 0, 0, 0);
            }
        }
    }
    // h2 = relu(acc2 + b2) -> bufB
    #pragma unroll
    for (int a = 0; a < 2; ++a) {
        int ot = 2*w + a;
        float4 bv = *reinterpret_cast<const float4*>(b2 + ot*16 + kg*4);
        int o0 = ot*16 + kg*4;
        #pragma unroll
        for (int pt = 0; pt < 4; ++pt) {
            f32x4 d = acc2[a][pt];
            int p = pt*16 + lp;
            uint2 q;
            q.x = (unsigned int)f2bf(fmaxf(d.x + bv.x, 0.f)) |
                  ((unsigned int)f2bf(fmaxf(d.y + bv.y, 0.f)) << 16);
            q.y = (unsigned int)f2bf(fmaxf(d.z + bv.z, 0.f)) |
                  ((unsigned int)f2bf(fmaxf(d.w + bv.w, 0.f)) << 16);
            *reinterpret_cast<uint2*>(&bufB[((o0 >> 3)*64 + p)*8 + (o0 & 7)]) = q;
        }
    }
    __syncthreads();

    // ---- L3 (256 -> 256): read bufB, write bufA ----
    f32x4 acc3[2][4];
    #pragma unroll
    for (int a = 0; a < 2; ++a)
        #pragma unroll
        for (int p = 0; p < 4; ++p) acc3[a][p] = (f32x4)0.f;
    for (int ks = 0; ks < 8; ++ks) {
        bf16x8 a0 = w3f[((2*w  )*8 + ks)*64 + lane];
        bf16x8 a1 = w3f[((2*w+1)*8 + ks)*64 + lane];
        #pragma unroll
        for (int pt = 0; pt < 4; ++pt) {
            bf16x8 b = pB[(ks*4 + kg)*64 + pt*16 + lp];
            acc3[0][pt] = __builtin_amdgcn_mfma_f32_16x16x32_bf16(a0, b, acc3[0][pt], 0, 0, 0);
            acc3[1][pt] = __builtin_amdgcn_mfma_f32_16x16x32_bf16(a1, b, acc3[1][pt], 0, 0, 0);
        }
    }
    #pragma unroll
    for (int a = 0; a < 2; ++a) {
        int ot = 2*w + a;
        float4 bv = *reinterpret_cast<const float4*>(b3 + ot*16 + kg*4);
        int o0 = ot*16 + kg*4;
        #pragma unroll
        for (int pt = 0; pt < 4; ++pt) {
            f32x4 d = acc3[a][pt];
            int p = pt*16 + lp;
            uint2 q;
            q.x = (unsigned int)f2bf(fmaxf(d.x + bv.x, 0.f)) |
                  ((unsigned int)f2bf(fmaxf(d.y + bv.y, 0.f)) << 16);
            q.y = (unsigned int)f2bf(fmaxf(d.z + bv.z, 0.f)) |
                  ((unsigned int)f2bf(fmaxf(d.w + bv.w, 0.f)) << 16);
            *reinterpret_cast<uint2*>(&bufA[((o0 >> 3)*64 + p)*8 + (o0 & 7)]) = q;
        }
    }
    __syncthreads();

    // ---- L4 (256 -> 128): read bufA, write bufB. wave w owns o-tile w. ----
    f32x4 acc4[4];
    #pragma unroll
    for (int p = 0; p < 4; ++p) acc4[p] = (f32x4)0.f;
    for (int ks = 0; ks < 8; ++ks) {
        bf16x8 a0 = w4f[(w*8 + ks)*64 + lane];
        #pragma unroll
        for (int pt = 0; pt < 4; ++pt) {
            bf16x8 b = pA[(ks*4 + kg)*64 + pt*16 + lp];
            acc4[pt] = __builtin_amdgcn_mfma_f32_16x16x32_bf16(a0, b, acc4[pt], 0, 0, 0);
        }
    }
    {
        int ot = w;
        float4 bv = *reinterpret_cast<const float4*>(b4 + ot*16 + kg*4);
        int o0 = ot*16 + kg*4;
        #pragma unroll
        for (int pt = 0; pt < 4; ++pt) {
            f32x4 d = acc4[pt];
            int p = pt*16 + lp;
            uint2 q;
            q.x = (unsigned int)f2bf(fmaxf(d.x + bv.x, 0.f)) |
                  ((unsigned int)f2bf(fmaxf(d.y + bv.y, 0.f)) << 16);
            q.y = (unsigned int)f2bf(fmaxf(d.z + bv.z, 0.f)) |
                  ((unsigned int)f2bf(fmaxf(d.w + bv.w, 0.f)) << 16);
            *reinterpret_cast<uint2*>(&bufB[((o0 >> 3)*64 + p)*8 + (o0 & 7)]) = q;
        }
    }
    __syncthreads();

    // ---- heads: MFMA on h4 (waves 0-3, pt=w), s1-dot fp32 (wave 4) ----
    f32x4 acch = (f32x4)0.f;
    if (w < 4) {
        for (int ks = 0; ks < 4; ++ks) {
            bf16x8 a0 = hpf[ks*64 + lane];
            bf16x8 b  = pB[(ks*4 + kg)*64 + w*16 + lp];
            acch = __builtin_amdgcn_mfma_f32_16x16x32_bf16(a0, b, acch, 0, 0, 0);
        }
    } else if (w == 4) {
        float part[10];
        #pragma unroll
        for (int c = 0; c < 10; ++c) part[c] = 0.f;
        const float* sf = s1 + bn * 256;
        #pragma unroll
        for (int t = 0; t < 4; ++t) {
            int k = lane + t*64;
            float sv = sf[k];
            #pragma unroll
            for (int c = 0; c < 8; ++c) part[c] = fmaf(regw[c*384 + k], sv, part[c]);
            part[8] = fmaf(clsw[k],       sv, part[8]);
            part[9] = fmaf(clsw[384 + k], sv, part[9]);
        }
        #pragma unroll
        for (int c = 0; c < 10; ++c) {
            float v = part[c];
            #pragma unroll
            for (int o2 = 1; o2 < 64; o2 <<= 1) v += __shfl_xor(v, o2, 64);
            if (lane == 0) sdot[c] = v;
        }
    }
    __syncthreads();

    // ---- dc contraction over the 64 slots ----
    if (w < 4) {
        int p = w*16 + lp;
        #pragma unroll
        for (int r = 0; r < 4; ++r) {
            int c = kg*4 + r;
            float v = 0.f;
            if (c < 10) {
                float hdot = acch[r] + sdot[c];
                float dw, hb;
                if (c < 8) { dw = dcrw[c*64 + p];     hb = regb[c];   }
                else       { dw = dccw[(c-8)*64 + p]; hb = clsb[c-8]; }
                v = (hdot + hb) * dw;
            }
            #pragma unroll
            for (int o2 = 1; o2 < 16; o2 <<= 1) v += __shfl_xor(v, o2, 64);
            if (lp == 0) pdc[w][c] = v;
        }
    }
    __syncthreads();
    if (tid < 16) {
        int c = tid;
        if (c < 10) {
            float s = pdc[0][c] + pdc[1][c] + pdc[2][c] + pdc[3][c];
            if (c < 8) outp[2048 + bn*8 + c] = s + dcrb[c];
            else       outp[bn*2 + (c-8)]    = s + dccb[c-8];
        }
    }
}

extern "C" void kernel_launch(void* const* d_in, const int* in_sizes, int n_in,
                              void* d_out, int out_size, void* d_ws, size_t ws_size,
                              hipStream_t stream)
{
    const float* grasp = (const float*)d_in[0];
    const float* pc    = (const float*)d_in[1];
    const float* s1    = (const float*)d_in[3];
    const float* W1 = (const float*)d_in[4];  const float* b1 = (const float*)d_in[5];
    const float* W2 = (const float*)d_in[6];  const float* b2 = (const float*)d_in[7];
    const float* W3 = (const float*)d_in[8];  const float* b3 = (const float*)d_in[9];
    const float* W4 = (const float*)d_in[10]; const float* b4 = (const float*)d_in[11];
    const float* regw = (const float*)d_in[12]; const float* regb = (const float*)d_in[13];
    const float* clsw = (const float*)d_in[14]; const float* clsb = (const float*)d_in[15];
    const float* dcrw = (const float*)d_in[16]; const float* dcrb = (const float*)d_in[17];
    const float* dccw = (const float*)d_in[18]; const float* dccb = (const float*)d_in[19];
    float* outp = (float*)d_out;
    // out layout: x_cls [0,2048) | x_reg [2048,10240) | mask [10240,11264)

    char* ws = (char*)d_ws;
    int*    idx  = (int*)ws;                                  // 786432 B
    int*    ucnt = (int*)(ws + 786432);                       // 4096 B
    float4* gpc  = (float4*)(ws + 790528);                    // 1 MiB
    unsigned short* W2p = (unsigned short*)(ws + 1839104);    // 262144 B
    unsigned short* W3p = (unsigned short*)(ws + 2101248);    // 131072 B
    unsigned short* W4p = (unsigned short*)(ws + 2232320);    //  65536 B
    unsigned short* Hp  = (unsigned short*)(ws + 2297856);    //   4096 B

    k_pack<<<128, 256, 0, stream>>>(W2, W3, W4, regw, clsw, W2p, W3p, W4p, Hp);
    k_ballq<<<1024, 256, 0, stream>>>(grasp, pc, idx, ucnt);
    k_transform<<<256, 256, 0, stream>>>(grasp, pc, idx, ucnt, gpc, outp + 10240);
    k_mlp<<<1024, 512, 0, stream>>>(gpc, s1, W1, b1, b2, b3, b4,
                                    W2p, W3p, W4p, Hp,
                                    regw, regb, clsw, clsb, dcrw, dcrb, dccw, dccb,
                                    outp);
}

// Round 3
// 208.786 us; speedup vs baseline: 10.3731x; 1.0313x over previous
//
#include <hip/hip_runtime.h>
#include <hip/hip_bf16.h>

// PointNet2Refine fused: [K0] weight pack -> [K1] ballq + transform + MFMA MLP.
// B=2, NUM=512, A=20000, Bn=1024, NUM_NEI=192, GRIPPER_NUM=64.

#define A_PTS   20000
#define BN_TOT  1024
#define NNEI    192
#define GNUM    64
#define R2      0.09f
#define CHUNKS  313   // ceil(20000/64)

typedef __attribute__((ext_vector_type(8))) short bf16x8;
typedef __attribute__((ext_vector_type(4))) float f32x4;

__device__ inline unsigned short f2bf(float v) {
    __hip_bfloat16 h = __float2bfloat16(v);
    return *reinterpret_cast<unsigned short*>(&h);
}

// ---------------- K0: pack weights to frag-linear bf16 ----------------------
// A-frag layout: dst[((ot*KS + ks)*64 + lane)*8 + e] = W[ot*16+(lane&15)]
//                                                      [ks*32+(lane>>4)*8+e]
// Same k-map is used for B-frags from LDS, so any k-map error cancels.
#define NW2 131072   // 16 ot * 16 ks * 512
#define NW3 65536    // 16 ot *  8 ks * 512
#define NW4 32768    //  8 ot *  8 ks * 512
#define NHP 2048     //  1 ot *  4 ks * 512
__global__ __launch_bounds__(256) void k_pack(const float* __restrict__ W2,
                                              const float* __restrict__ W3,
                                              const float* __restrict__ W4,
                                              const float* __restrict__ regw,
                                              const float* __restrict__ clsw,
                                              unsigned short* __restrict__ W2p,
                                              unsigned short* __restrict__ W3p,
                                              unsigned short* __restrict__ W4p,
                                              unsigned short* __restrict__ Hp)
{
    int stride = gridDim.x * blockDim.x;
    for (int t = blockIdx.x * blockDim.x + threadIdx.x;
         t < NW2 + NW3 + NW4 + NHP; t += stride) {
        const float* src; unsigned short* dst; int KS, K, i;
        if (t < NW2)                   { src = W2; dst = W2p; KS = 16; K = 512; i = t; }
        else if (t < NW2+NW3)          { src = W3; dst = W3p; KS = 8;  K = 256; i = t-NW2; }
        else if (t < NW2+NW3+NW4)      { src = W4; dst = W4p; KS = 8;  K = 256; i = t-NW2-NW3; }
        else {
            int i2 = t - NW2 - NW3 - NW4;
            int ks = i2 / 512, r = i2 % 512, l = r >> 3, e = r & 7;
            int c = l & 15;
            int k = 256 + ks*32 + ((l >> 4) << 3) + e;
            float v = 0.f;
            if (c < 8)       v = regw[c*384 + k];
            else if (c < 10) v = clsw[(c-8)*384 + k];
            Hp[i2] = f2bf(v);
            continue;
        }
        int ot = i / (KS*512), rem = i % (KS*512);
        int ks = rem / 512, r = rem % 512, l = r >> 3, e = r & 7;
        int o = ot*16 + (l & 15);
        int k = ks*32 + ((l >> 4) << 3) + e;
        dst[i] = f2bf(src[o*K + k]);
    }
}

// ---------------- K1: fused ballq + transform + MLP + heads -----------------
// One block = one bn row. 512 thr = 8 waves. Ball query masks + neighbor list
// + transformed gripper points all stay in LDS; only final outputs go global.
__global__ __launch_bounds__(512, 4) void k_fused(
    const float* __restrict__ grasp, const float* __restrict__ pc,
    const float* __restrict__ s1,
    const float* __restrict__ W1, const float* __restrict__ b1,
    const float* __restrict__ b2, const float* __restrict__ b3,
    const float* __restrict__ b4,
    const unsigned short* __restrict__ W2p, const unsigned short* __restrict__ W3p,
    const unsigned short* __restrict__ W4p, const unsigned short* __restrict__ Hp,
    const float* __restrict__ regw, const float* __restrict__ regb,
    const float* __restrict__ clsw, const float* __restrict__ clsb,
    const float* __restrict__ dcrw, const float* __restrict__ dcrb,
    const float* __restrict__ dccw, const float* __restrict__ dccb,
    float* __restrict__ outp)
{
    __shared__ __align__(16) unsigned short bufA[32*64*8];   // 32 KiB
    __shared__ __align__(16) unsigned short bufB[32*64*8];   // 32 KiB
    __shared__ float sdot[16];
    __shared__ float pdc[4][16];
    __shared__ unsigned long long masks[CHUNKS];             // 2504 B
    __shared__ int soff[CHUNKS];                             // 1252 B
    __shared__ int idx_sh[NNEI];                             // 768 B
    __shared__ float4 tval[NNEI];                            // 3072 B
    __shared__ float4 gp[GNUM];                              // 1024 B
    __shared__ unsigned long long tmask[3];
    __shared__ int sh_total, sh_pad;

    int bn   = blockIdx.x;
    int tid  = threadIdx.x;
    int lane = tid & 63;
    int w    = tid >> 6;      // 0..7

    const float* g = grasp + bn * 8;
    float g0=g[0], g1=g[1], g2=g[2], g3=g[3], g4=g[4], g5=g[5], g6=g[6], g7=g[7];
    float cx=g0, cy=g1, cz=g2;
    const float* pcb = pc + (bn >> 9) * (A_PTS * 6);

    // ================= Phase B: ball query =================
    float cc = cx*cx + cy*cy + cz*cz;
    for (int c = w; c < CHUNKS; c += 8) {
        int a = c * 64 + lane;
        bool valid = false;
        if (a < A_PTS) {
            const float2* pp2 = reinterpret_cast<const float2*>(pcb + a * 6);
            float2 v01 = pp2[0];
            float  pz  = pcb[a*6 + 2];
            float px = v01.x, py = v01.y;
            float xx = px*px + py*py + pz*pz;
            float dt = cx*px + cy*py + cz*pz;
            valid = (cc + xx - 2.0f * dt) < R2;   // match reference formula
        }
        unsigned long long mb = __ballot(valid);
        if (lane == 0) masks[c] = mb;
    }
    __syncthreads();

    if (w == 0) {   // prefix scan of chunk popcounts, ordered
        int c0 = lane * 5;
        int cnts[5]; int s = 0;
        #pragma unroll
        for (int i = 0; i < 5; ++i) {
            int c = c0 + i;
            int v = (c < CHUNKS) ? __popcll(masks[c]) : 0;
            cnts[i] = v; s += v;
        }
        int incl = s;
        for (int o2 = 1; o2 < 64; o2 <<= 1) {
            int v = __shfl_up(incl, o2, 64);
            if (lane >= o2) incl += v;
        }
        int run = incl - s;
        #pragma unroll
        for (int i = 0; i < 5; ++i) {
            int c = c0 + i;
            if (c < CHUNKS) soff[c] = run;
            run += cnts[i];
        }
        int total = __shfl(incl, 63, 64);
        int fc = 0x7fffffff;
        #pragma unroll
        for (int i = 0; i < 5; ++i) {
            int c = c0 + i;
            if (c < CHUNKS && masks[c] != 0ull) { fc = c; break; }
        }
        for (int o2 = 32; o2 >= 1; o2 >>= 1) fc = min(fc, __shfl_xor(fc, o2, 64));
        if (lane == 0) {
            sh_total = total;
            sh_pad = (fc == 0x7fffffff) ? 0
                     : fc * 64 + (int)__builtin_ctzll(masks[fc]);
        }
    }
    __syncthreads();

    int total = sh_total, padval = sh_pad;
    for (int c = w; c < CHUNKS; c += 8) {
        unsigned long long mb = masks[c];
        int base = soff[c];
        if (mb != 0ull && base < NNEI && ((mb >> lane) & 1ull)) {
            int pos = base + __popcll(mb & ((1ull << lane) - 1ull));
            if (pos < NNEI) idx_sh[pos] = c * 64 + lane;
        }
    }
    int cnt = total < NNEI ? total : NNEI;
    for (int p = cnt + tid; p < NNEI; p += 512) idx_sh[p] = padval;
    __syncthreads();

    // ================= Phase T: gripper transform =================
    float gsum = g0+g1+g2+g3+g4+g5+g6+g7;
    bool gmask = (gsum != -8.0f);
    float ay0=g3, ay1=g4, ay2=g5;
    float cth = cosf(g6), sth = sinf(g6);
    float ny = sqrtf(ay0*ay0 + ay1*ay1 + ay2*ay2) + 1e-12f;
    ay0/=ny; ay1/=ny; ay2/=ny;
    float ax0=ay1, ax1=-ay0;
    float nx = sqrtf(ax0*ax0 + ax1*ax1) + 1e-12f;
    ax0/=nx; ax1/=nx;
    float az0 =  ax1*ay2;
    float az1 = -ax0*ay2;
    float az2 =  ax0*ay1 - ax1*ay0;
    float nz = sqrtf(az0*az0 + az1*az1 + az2*az2);
    if (nz == 0.0f) { az0=0.f; az1=0.f; az2=1.f; }
    else            { az0/=nz; az1/=nz; az2/=nz; }
    float ap0 = ax0*cth + az0*sth;
    float ap1 = ax1*cth + az1*sth;
    float ap2 =           az2*sth;
    float na = sqrtf(ap0*ap0 + ap1*ap1 + ap2*ap2) + 1e-12f;
    ap0/=na; ap1/=na; ap2/=na;
    float mi0 = ap1*ay2 - ap2*ay1;
    float mi1 = ap2*ay0 - ap0*ay2;
    float mi2 = ap0*ay1 - ap1*ay0;

    bool inside = false;
    if (tid < NNEI) {
        int ai = idx_sh[tid];
        const float* pp = pcb + ai * 6;
        float qx = pp[0]-cx, qy = pp[1]-cy, qz = pp[2]-cz;
        float tx = ap0*qx + ap1*qy + ap2*qz;
        float ty = ay0*qx + ay1*qy + ay2*qz;
        float tz = mi0*qx + mi1*qy + mi2*qz;
        inside = (tx > 0.f) && (tx < 0.3f) && (ty > -0.15f) && (ty < 0.15f)
              && (tz > -0.1f) && (tz < 0.1f);
        tval[tid] = make_float4(tx, ty, tz, 0.f);
    }
    unsigned long long mb = __ballot(inside);
    if (lane == 0 && w < 3) tmask[w] = mb;
    __syncthreads();

    unsigned long long m0 = tmask[0], m1 = tmask[1], m2 = tmask[2];
    int c0 = __popcll(m0), c1 = __popcll(m1), c2 = __popcll(m2);
    int tfound = c0 + c1 + c2;
    int firstj = 0;
    if (m0)      firstj = (int)__builtin_ctzll(m0);
    else if (m1) firstj = 64 + (int)__builtin_ctzll(m1);
    else if (m2) firstj = 128 + (int)__builtin_ctzll(m2);
    float4 padv = tval[firstj];

    if (tid < NNEI && inside) {
        int wbase = (w == 0) ? 0 : (w == 1 ? c0 : c0 + c1);
        int rank = wbase + __popcll(mb & ((1ull << lane) - 1ull));
        if (rank < GNUM) gp[rank] = tval[tid];
    }
    int gcnt = tfound < GNUM ? tfound : GNUM;
    for (int p = gcnt + tid; p < GNUM; p += 512) gp[p] = padv;
    if (tid == 0)
        outp[10240 + bn] = (total > 0 && tfound > 0 && gmask) ? 1.0f : 0.0f;
    __syncthreads();

    // ================= Phase M: MFMA MLP + heads =================
    int kg = lane >> 4;     // 0..3
    int lp = lane & 15;

    const bf16x8* pA  = reinterpret_cast<const bf16x8*>(bufA);
    const bf16x8* pB  = reinterpret_cast<const bf16x8*>(bufB);
    const bf16x8* w2f = reinterpret_cast<const bf16x8*>(W2p);
    const bf16x8* w3f = reinterpret_cast<const bf16x8*>(W3p);
    const bf16x8* w4f = reinterpret_cast<const bf16x8*>(W4p);
    const bf16x8* hpf = reinterpret_cast<const bf16x8*>(Hp);

    float4 P = gp[lane];

    // ---- L1 (fp32 VALU) + L2 (MFMA, K=512 in two 256 halves) ----
    f32x4 acc2[2][4];
    #pragma unroll
    for (int a = 0; a < 2; ++a)
        #pragma unroll
        for (int p = 0; p < 4; ++p) acc2[a][p] = (f32x4)0.f;

    for (int h = 0; h < 2; ++h) {
        __syncthreads();
        #pragma unroll
        for (int i = 0; i < 4; ++i) {
            int ob = w + 8*i;                 // local o-block 0..31
            unsigned int u[4];
            #pragma unroll
            for (int jj = 0; jj < 4; ++jj) {
                int o = h*256 + ob*8 + jj*2;
                float v0 = fmaxf(W1[3*o  ]*P.x + W1[3*o+1]*P.y + W1[3*o+2]*P.z + b1[o], 0.f);
                float v1 = fmaxf(W1[3*o+3]*P.x + W1[3*o+4]*P.y + W1[3*o+5]*P.z + b1[o+1], 0.f);
                u[jj] = (unsigned int)f2bf(v0) | ((unsigned int)f2bf(v1) << 16);
            }
            uint4 q = make_uint4(u[0], u[1], u[2], u[3]);
            *reinterpret_cast<uint4*>(&bufA[(ob*64 + lane)*8]) = q;
        }
        __syncthreads();
        for (int ks = 0; ks < 8; ++ks) {
            int ksg = h*8 + ks;
            bf16x8 a0 = w2f[((2*w  )*16 + ksg)*64 + lane];
            bf16x8 a1 = w2f[((2*w+1)*16 + ksg)*64 + lane];
            __builtin_amdgcn_s_setprio(1);
            #pragma unroll
            for (int pt = 0; pt < 4; ++pt) {
                bf16x8 b = pA[(ks*4 + kg)*64 + pt*16 + lp];
                acc2[0][pt] = __builtin_amdgcn_mfma_f32_16x16x32_bf16(a0, b, acc2[0][pt], 0, 0, 0);
                acc2[1][pt] = __builtin_amdgcn_mfma_f32_16x16x32_bf16(a1, b, acc2[1][pt], 0, 0, 0);
            }
            __builtin_amdgcn_s_setprio(0);
        }
    }
    #pragma unroll
    for (int a = 0; a < 2; ++a) {
        int ot = 2*w + a;
        float4 bv = *reinterpret_cast<const float4*>(b2 + ot*16 + kg*4);
        int o0 = ot*16 + kg*4;
        #pragma unroll
        for (int pt = 0; pt < 4; ++pt) {
            f32x4 d = acc2[a][pt];
            int p = pt*16 + lp;
            uint2 q;
            q.x = (unsigned int)f2bf(fmaxf(d.x + bv.x, 0.f)) |
                  ((unsigned int)f2bf(fmaxf(d.y + bv.y, 0.f)) << 16);
            q.y = (unsigned int)f2bf(fmaxf(d.z + bv.z, 0.f)) |
                  ((unsigned int)f2bf(fmaxf(d.w + bv.w, 0.f)) << 16);
            *reinterpret_cast<uint2*>(&bufB[((o0 >> 3)*64 + p)*8 + (o0 & 7)]) = q;
        }
    }
    __syncthreads();

    // ---- L3 (256 -> 256): read bufB, write bufA ----
    f32x4 acc3[2][4];
    #pragma unroll
    for (int a = 0; a < 2; ++a)
        #pragma unroll
        for (int p = 0; p < 4; ++p) acc3[a][p] = (f32x4)0.f;
    for (int ks = 0; ks < 8; ++ks) {
        bf16x8 a0 = w3f[((2*w  )*8 + ks)*64 + lane];
        bf16x8 a1 = w3f[((2*w+1)*8 + ks)*64 + lane];
        __builtin_amdgcn_s_setprio(1);
        #pragma unroll
        for (int pt = 0; pt < 4; ++pt) {
            bf16x8 b = pB[(ks*4 + kg)*64 + pt*16 + lp];
            acc3[0][pt] = __builtin_amdgcn_mfma_f32_16x16x32_bf16(a0, b, acc3[0][pt], 0, 0, 0);
            acc3[1][pt] = __builtin_amdgcn_mfma_f32_16x16x32_bf16(a1, b, acc3[1][pt], 0, 0, 0);
        }
        __builtin_amdgcn_s_setprio(0);
    }
    #pragma unroll
    for (int a = 0; a < 2; ++a) {
        int ot = 2*w + a;
        float4 bv = *reinterpret_cast<const float4*>(b3 + ot*16 + kg*4);
        int o0 = ot*16 + kg*4;
        #pragma unroll
        for (int pt = 0; pt < 4; ++pt) {
            f32x4 d = acc3[a][pt];
            int p = pt*16 + lp;
            uint2 q;
            q.x = (unsigned int)f2bf(fmaxf(d.x + bv.x, 0.f)) |
                  ((unsigned int)f2bf(fmaxf(d.y + bv.y, 0.f)) << 16);
            q.y = (unsigned int)f2bf(fmaxf(d.z + bv.z, 0.f)) |
                  ((unsigned int)f2bf(fmaxf(d.w + bv.w, 0.f)) << 16);
            *reinterpret_cast<uint2*>(&bufA[((o0 >> 3)*64 + p)*8 + (o0 & 7)]) = q;
        }
    }
    __syncthreads();

    // ---- L4 (256 -> 128): read bufA, write bufB. wave w owns o-tile w. ----
    f32x4 acc4[4];
    #pragma unroll
    for (int p = 0; p < 4; ++p) acc4[p] = (f32x4)0.f;
    for (int ks = 0; ks < 8; ++ks) {
        bf16x8 a0 = w4f[(w*8 + ks)*64 + lane];
        __builtin_amdgcn_s_setprio(1);
        #pragma unroll
        for (int pt = 0; pt < 4; ++pt) {
            bf16x8 b = pA[(ks*4 + kg)*64 + pt*16 + lp];
            acc4[pt] = __builtin_amdgcn_mfma_f32_16x16x32_bf16(a0, b, acc4[pt], 0, 0, 0);
        }
        __builtin_amdgcn_s_setprio(0);
    }
    {
        int ot = w;
        float4 bv = *reinterpret_cast<const float4*>(b4 + ot*16 + kg*4);
        int o0 = ot*16 + kg*4;
        #pragma unroll
        for (int pt = 0; pt < 4; ++pt) {
            f32x4 d = acc4[pt];
            int p = pt*16 + lp;
            uint2 q;
            q.x = (unsigned int)f2bf(fmaxf(d.x + bv.x, 0.f)) |
                  ((unsigned int)f2bf(fmaxf(d.y + bv.y, 0.f)) << 16);
            q.y = (unsigned int)f2bf(fmaxf(d.z + bv.z, 0.f)) |
                  ((unsigned int)f2bf(fmaxf(d.w + bv.w, 0.f)) << 16);
            *reinterpret_cast<uint2*>(&bufB[((o0 >> 3)*64 + p)*8 + (o0 & 7)]) = q;
        }
    }
    __syncthreads();

    // ---- heads: MFMA on h4 (waves 0-3, pt=w), s1-dot fp32 (wave 4) ----
    f32x4 acch = (f32x4)0.f;
    if (w < 4) {
        for (int ks = 0; ks < 4; ++ks) {
            bf16x8 a0 = hpf[ks*64 + lane];
            bf16x8 b  = pB[(ks*4 + kg)*64 + w*16 + lp];
            acch = __builtin_amdgcn_mfma_f32_16x16x32_bf16(a0, b, acch, 0, 0, 0);
        }
    } else if (w == 4) {
        float part[10];
        #pragma unroll
        for (int c = 0; c < 10; ++c) part[c] = 0.f;
        const float* sf = s1 + bn * 256;
        #pragma unroll
        for (int t = 0; t < 4; ++t) {
            int k = lane + t*64;
            float sv = sf[k];
            #pragma unroll
            for (int c = 0; c < 8; ++c) part[c] = fmaf(regw[c*384 + k], sv, part[c]);
            part[8] = fmaf(clsw[k],       sv, part[8]);
            part[9] = fmaf(clsw[384 + k], sv, part[9]);
        }
        #pragma unroll
        for (int c = 0; c < 10; ++c) {
            float v = part[c];
            #pragma unroll
            for (int o2 = 1; o2 < 64; o2 <<= 1) v += __shfl_xor(v, o2, 64);
            if (lane == 0) sdot[c] = v;
        }
    }
    __syncthreads();

    // ---- dc contraction over the 64 slots ----
    if (w < 4) {
        int p = w*16 + lp;
        #pragma unroll
        for (int r = 0; r < 4; ++r) {
            int c = kg*4 + r;
            float v = 0.f;
            if (c < 10) {
                float hdot = acch[r] + sdot[c];
                float dw, hb;
                if (c < 8) { dw = dcrw[c*64 + p];     hb = regb[c];   }
                else       { dw = dccw[(c-8)*64 + p]; hb = clsb[c-8]; }
                v = (hdot + hb) * dw;
            }
            #pragma unroll
            for (int o2 = 1; o2 < 16; o2 <<= 1) v += __shfl_xor(v, o2, 64);
            if (lp == 0) pdc[w][c] = v;
        }
    }
    __syncthreads();
    if (tid < 16) {
        int c = tid;
        if (c < 10) {
            float s = pdc[0][c] + pdc[1][c] + pdc[2][c] + pdc[3][c];
            if (c < 8) outp[2048 + bn*8 + c] = s + dcrb[c];
            else       outp[bn*2 + (c-8)]    = s + dccb[c-8];
        }
    }
}

extern "C" void kernel_launch(void* const* d_in, const int* in_sizes, int n_in,
                              void* d_out, int out_size, void* d_ws, size_t ws_size,
                              hipStream_t stream)
{
    const float* grasp = (const float*)d_in[0];
    const float* pc    = (const float*)d_in[1];
    const float* s1    = (const float*)d_in[3];
    const float* W1 = (const float*)d_in[4];  const float* b1 = (const float*)d_in[5];
    const float* W2 = (const float*)d_in[6];  const float* b2 = (const float*)d_in[7];
    const float* W3 = (const float*)d_in[8];  const float* b3 = (const float*)d_in[9];
    const float* W4 = (const float*)d_in[10]; const float* b4 = (const float*)d_in[11];
    const float* regw = (const float*)d_in[12]; const float* regb = (const float*)d_in[13];
    const float* clsw = (const float*)d_in[14]; const float* clsb = (const float*)d_in[15];
    const float* dcrw = (const float*)d_in[16]; const float* dcrb = (const float*)d_in[17];
    const float* dccw = (const float*)d_in[18]; const float* dccb = (const float*)d_in[19];
    float* outp = (float*)d_out;
    // out layout: x_cls [0,2048) | x_reg [2048,10240) | mask [10240,11264)

    char* ws = (char*)d_ws;
    unsigned short* W2p = (unsigned short*)ws;                // 262144 B
    unsigned short* W3p = (unsigned short*)(ws + 262144);     // 131072 B
    unsigned short* W4p = (unsigned short*)(ws + 393216);     //  65536 B
    unsigned short* Hp  = (unsigned short*)(ws + 458752);     //   4096 B

    k_pack<<<904, 256, 0, stream>>>(W2, W3, W4, regw, clsw, W2p, W3p, W4p, Hp);
    k_fused<<<1024, 512, 0, stream>>>(grasp, pc, s1, W1, b1, b2, b3, b4,
                                      W2p, W3p, W4p, Hp,
                                      regw, regb, clsw, clsb, dcrw, dcrb, dccw, dccb,
                                      outp);
}

// Round 5
// 193.158 us; speedup vs baseline: 11.2123x; 1.0809x over previous
//
#include <hip/hip_runtime.h>
#include <hip/hip_bf16.h>

// PointNet2Refine fused: [K0] pack (coalesced) + xyzw table -> [K1] fused
// ballq + transform + full-MFMA MLP. B=2, NUM=512, A=20000, Bn=1024.

#define A_PTS   20000
#define BN_TOT  1024
#define NNEI    192
#define GNUM    64
#define R2      0.09f
#define CHUNKS  313   // ceil(20000/64)

typedef __attribute__((ext_vector_type(8))) short bf16x8;
typedef __attribute__((ext_vector_type(4))) float f32x4;

__device__ inline unsigned short f2bf(float v) {
    __hip_bfloat16 h = __float2bfloat16(v);
    return *reinterpret_cast<unsigned short*>(&h);
}

// ---------------- K0: pack weights (coalesced) + xyzw table -----------------
// Frag layout (consumer contract, unchanged since round 2):
//   dst[((ot*KS + ks)*64 + l)*8 + e] = W[ot*16 + (l&15)][ks*32 + (l>>4)*8 + e]
// Producer: thread owns (o, k4): reads float4 W[o][4k4..4k4+3] (coalesced
// 16B), writes ushort4 at l=kg*16+lp, e0=k&7 (8B aligned). Same mapping.
// Section table (FIXED from round 4: W2 is 256 rows x 512 cols = 32768 float4).
#define P_W2_END 32768            // 256 o * 128 k4
#define P_W3_END 49152            // + 256 o * 64 k4
#define P_W4_END 57344            // + 128 o * 64 k4
#define P_HP_END 59392            // + 2048 elementwise
#define P_W1_END 75776            // + 32 ot * 512 elementwise (W1 + b1 at k=3)
#define P_XW_END 115776           // + 40000 points
__global__ __launch_bounds__(256) void k_pack(
    const float* __restrict__ W1, const float* __restrict__ b1,
    const float* __restrict__ W2, const float* __restrict__ W3,
    const float* __restrict__ W4,
    const float* __restrict__ regw, const float* __restrict__ clsw,
    const float* __restrict__ pc,
    unsigned short* __restrict__ W2p, unsigned short* __restrict__ W3p,
    unsigned short* __restrict__ W4p, unsigned short* __restrict__ Hp,
    unsigned short* __restrict__ W1p, float4* __restrict__ xyzw)
{
    int t = blockIdx.x * 256 + threadIdx.x;
    if (t < P_W2_END) {
        int o = t >> 7, k = (t & 127) << 2;          // o in [0,256), k in [0,512)
        float4 v = *reinterpret_cast<const float4*>(W2 + o*512 + k);
        int ot=o>>4, lp=o&15, ks=k>>5, kg=(k>>3)&3, e0=k&7;
        int d = ((ot*16 + ks)*64 + kg*16 + lp)*8 + e0;
        *reinterpret_cast<ushort4*>(W2p + d) =
            make_ushort4(f2bf(v.x), f2bf(v.y), f2bf(v.z), f2bf(v.w));
    } else if (t < P_W3_END) {
        int i = t - P_W2_END;
        int o = i >> 6, k = (i & 63) << 2;           // o in [0,256), k in [0,256)
        float4 v = *reinterpret_cast<const float4*>(W3 + o*256 + k);
        int ot=o>>4, lp=o&15, ks=k>>5, kg=(k>>3)&3, e0=k&7;
        int d = ((ot*8 + ks)*64 + kg*16 + lp)*8 + e0;
        *reinterpret_cast<ushort4*>(W3p + d) =
            make_ushort4(f2bf(v.x), f2bf(v.y), f2bf(v.z), f2bf(v.w));
    } else if (t < P_W4_END) {
        int i = t - P_W3_END;
        int o = i >> 6, k = (i & 63) << 2;           // o in [0,128), k in [0,256)
        float4 v = *reinterpret_cast<const float4*>(W4 + o*256 + k);
        int ot=o>>4, lp=o&15, ks=k>>5, kg=(k>>3)&3, e0=k&7;
        int d = ((ot*8 + ks)*64 + kg*16 + lp)*8 + e0;
        *reinterpret_cast<ushort4*>(W4p + d) =
            make_ushort4(f2bf(v.x), f2bf(v.y), f2bf(v.z), f2bf(v.w));
    } else if (t < P_HP_END) {
        int i2 = t - P_W4_END;
        int ks = i2 >> 9, r = i2 & 511, l = r >> 3, e = r & 7;
        int c = l & 15;
        int k = 256 + ks*32 + ((l >> 4) << 3) + e;
        float v = 0.f;
        if (c < 8)       v = regw[c*384 + k];
        else if (c < 10) v = clsw[(c-8)*384 + k];
        Hp[i2] = f2bf(v);
    } else if (t < P_W1_END) {
        int i = t - P_HP_END;
        int ot = i >> 9, r = i & 511, l = r >> 3, e = r & 7;
        int o = ot*16 + (l & 15);
        int k = ((l >> 4) << 3) + e;
        float v = (k < 3) ? W1[o*3 + k] : (k == 3 ? b1[o] : 0.f);
        W1p[i] = f2bf(v);
    } else if (t < P_XW_END) {
        int i = t - P_W1_END;
        int b = (i >= A_PTS) ? 1 : 0;
        int a = i - b * A_PTS;
        const float* pp = pc + b*(A_PTS*6) + a*6;
        float x = pp[0], y = pp[1], z = pp[2];
        xyzw[i] = make_float4(x, y, z, x*x + y*y + z*z);
    }
}

// ---------------- K1: fused ballq + transform + MLP + heads -----------------
// One block = one bn row. 512 thr = 8 waves. All intermediates in LDS.
__global__ __launch_bounds__(512, 4) void k_fused(
    const float* __restrict__ grasp, const float4* __restrict__ xyzw,
    const float* __restrict__ s1,
    const float* __restrict__ b2, const float* __restrict__ b3,
    const float* __restrict__ b4,
    const unsigned short* __restrict__ W2p, const unsigned short* __restrict__ W3p,
    const unsigned short* __restrict__ W4p, const unsigned short* __restrict__ Hp,
    const unsigned short* __restrict__ W1p,
    const float* __restrict__ regw, const float* __restrict__ regb,
    const float* __restrict__ clsw, const float* __restrict__ clsb,
    const float* __restrict__ dcrw, const float* __restrict__ dcrb,
    const float* __restrict__ dccw, const float* __restrict__ dccb,
    float* __restrict__ outp)
{
    __shared__ __align__(16) unsigned short bufA[32*64*8];   // 32 KiB
    __shared__ __align__(16) unsigned short bufB[32*64*8];   // 32 KiB
    __shared__ float sdot[16];
    __shared__ float pdc[4][16];
    __shared__ unsigned long long masks[CHUNKS];
    __shared__ int soff[CHUNKS];
    __shared__ int idx_sh[NNEI];
    __shared__ float4 tval[NNEI];
    __shared__ float4 gp[GNUM];
    __shared__ unsigned long long tmask[3];
    __shared__ int sh_total, sh_pad;

    int bn   = blockIdx.x;
    int tid  = threadIdx.x;
    int lane = tid & 63;
    int w    = tid >> 6;      // 0..7

    const float* g = grasp + bn * 8;
    float g0=g[0], g1=g[1], g2=g[2], g3=g[3], g4=g[4], g5=g[5], g6=g[6], g7=g[7];
    float cx=g0, cy=g1, cz=g2;
    const float4* xw = xyzw + (bn >> 9) * A_PTS;

    // ================= Phase B: ball query =================
    float cc = cx*cx + cy*cy + cz*cz;
    for (int c = w; c < CHUNKS; c += 8) {
        int a = c * 64 + lane;
        bool valid = false;
        if (a < A_PTS) {
            float4 q = xw[a];
            float dt = cx*q.x + cy*q.y + cz*q.z;
            valid = (cc + q.w - 2.0f * dt) < R2;   // match reference formula
        }
        unsigned long long mb = __ballot(valid);
        if (lane == 0) masks[c] = mb;
    }
    __syncthreads();

    if (w == 0) {   // ordered prefix scan of chunk popcounts
        int c0 = lane * 5;
        int cnts[5]; int s = 0;
        #pragma unroll
        for (int i = 0; i < 5; ++i) {
            int c = c0 + i;
            int v = (c < CHUNKS) ? __popcll(masks[c]) : 0;
            cnts[i] = v; s += v;
        }
        int incl = s;
        for (int o2 = 1; o2 < 64; o2 <<= 1) {
            int v = __shfl_up(incl, o2, 64);
            if (lane >= o2) incl += v;
        }
        int run = incl - s;
        #pragma unroll
        for (int i = 0; i < 5; ++i) {
            int c = c0 + i;
            if (c < CHUNKS) soff[c] = run;
            run += cnts[i];
        }
        int total = __shfl(incl, 63, 64);
        int fc = 0x7fffffff;
        #pragma unroll
        for (int i = 0; i < 5; ++i) {
            int c = c0 + i;
            if (c < CHUNKS && masks[c] != 0ull) { fc = c; break; }
        }
        for (int o2 = 32; o2 >= 1; o2 >>= 1) fc = min(fc, __shfl_xor(fc, o2, 64));
        if (lane == 0) {
            sh_total = total;
            sh_pad = (fc == 0x7fffffff) ? 0
                     : fc * 64 + (int)__builtin_ctzll(masks[fc]);
        }
    }
    __syncthreads();

    int total = sh_total, padval = sh_pad;
    for (int c = w; c < CHUNKS; c += 8) {
        unsigned long long mb = masks[c];
        int base = soff[c];
        if (mb != 0ull && base < NNEI && ((mb >> lane) & 1ull)) {
            int pos = base + __popcll(mb & ((1ull << lane) - 1ull));
            if (pos < NNEI) idx_sh[pos] = c * 64 + lane;
        }
    }
    int cnt = total < NNEI ? total : NNEI;
    for (int p = cnt + tid; p < NNEI; p += 512) idx_sh[p] = padval;
    __syncthreads();

    // ================= Phase T: gripper transform =================
    float gsum = g0+g1+g2+g3+g4+g5+g6+g7;
    bool gmask = (gsum != -8.0f);
    float ay0=g3, ay1=g4, ay2=g5;
    float cth = cosf(g6), sth = sinf(g6);
    float ny = sqrtf(ay0*ay0 + ay1*ay1 + ay2*ay2) + 1e-12f;
    ay0/=ny; ay1/=ny; ay2/=ny;
    float ax0=ay1, ax1=-ay0;
    float nx = sqrtf(ax0*ax0 + ax1*ax1) + 1e-12f;
    ax0/=nx; ax1/=nx;
    float az0 =  ax1*ay2;
    float az1 = -ax0*ay2;
    float az2 =  ax0*ay1 - ax1*ay0;
    float nz = sqrtf(az0*az0 + az1*az1 + az2*az2);
    if (nz == 0.0f) { az0=0.f; az1=0.f; az2=1.f; }
    else            { az0/=nz; az1/=nz; az2/=nz; }
    float ap0 = ax0*cth + az0*sth;
    float ap1 = ax1*cth + az1*sth;
    float ap2 =           az2*sth;
    float na = sqrtf(ap0*ap0 + ap1*ap1 + ap2*ap2) + 1e-12f;
    ap0/=na; ap1/=na; ap2/=na;
    float mi0 = ap1*ay2 - ap2*ay1;
    float mi1 = ap2*ay0 - ap0*ay2;
    float mi2 = ap0*ay1 - ap1*ay0;

    bool inside = false;
    if (tid < NNEI) {
        float4 Q = xw[idx_sh[tid]];
        float qx = Q.x-cx, qy = Q.y-cy, qz = Q.z-cz;
        float tx = ap0*qx + ap1*qy + ap2*qz;
        float ty = ay0*qx + ay1*qy + ay2*qz;
        float tz = mi0*qx + mi1*qy + mi2*qz;
        inside = (tx > 0.f) && (tx < 0.3f) && (ty > -0.15f) && (ty < 0.15f)
              && (tz > -0.1f) && (tz < 0.1f);
        tval[tid] = make_float4(tx, ty, tz, 0.f);
    }
    unsigned long long mb = __ballot(inside);
    if (lane == 0 && w < 3) tmask[w] = mb;
    __syncthreads();

    unsigned long long m0 = tmask[0], m1 = tmask[1], m2 = tmask[2];
    int c0 = __popcll(m0), c1 = __popcll(m1), c2 = __popcll(m2);
    int tfound = c0 + c1 + c2;
    int firstj = 0;
    if (m0)      firstj = (int)__builtin_ctzll(m0);
    else if (m1) firstj = 64 + (int)__builtin_ctzll(m1);
    else if (m2) firstj = 128 + (int)__builtin_ctzll(m2);
    float4 padv = tval[firstj];

    if (tid < NNEI && inside) {
        int wbase = (w == 0) ? 0 : (w == 1 ? c0 : c0 + c1);
        int rank = wbase + __popcll(mb & ((1ull << lane) - 1ull));
        if (rank < GNUM) gp[rank] = tval[tid];
    }
    int gcnt = tfound < GNUM ? tfound : GNUM;
    for (int p = gcnt + tid; p < GNUM; p += 512) gp[p] = padv;
    if (tid == 0)
        outp[10240 + bn] = (total > 0 && tfound > 0 && gmask) ? 1.0f : 0.0f;
    __syncthreads();

    // ================= Phase M: MFMA MLP + heads =================
    int kg = lane >> 4;     // 0..3
    int lp = lane & 15;

    const bf16x8* pA  = reinterpret_cast<const bf16x8*>(bufA);
    const bf16x8* pB  = reinterpret_cast<const bf16x8*>(bufB);
    const bf16x8* w1f = reinterpret_cast<const bf16x8*>(W1p);
    const bf16x8* w2f = reinterpret_cast<const bf16x8*>(W2p);
    const bf16x8* w3f = reinterpret_cast<const bf16x8*>(W3p);
    const bf16x8* w4f = reinterpret_cast<const bf16x8*>(W4p);
    const bf16x8* hpf = reinterpret_cast<const bf16x8*>(Hp);

    // B-frag for L1: point coords at assumed-k {0,1,2}, 1.0 at k=3 (bias row).
    bf16x8 bfr[4];
    #pragma unroll
    for (int pt = 0; pt < 4; ++pt) {
        float4 Pp = gp[pt*16 + lp];
        bf16x8 b = (bf16x8)(short)0;
        if (kg == 0) {
            b[0] = (short)f2bf(Pp.x);
            b[1] = (short)f2bf(Pp.y);
            b[2] = (short)f2bf(Pp.z);
            b[3] = (short)0x3F80;      // bf16(1.0)
        }
        bfr[pt] = b;
    }

    // ---- L1 (MFMA, K-padded 3+bias) + L2 (MFMA, K=512 in two halves) ----
    f32x4 acc2[2][4];
    #pragma unroll
    for (int a = 0; a < 2; ++a)
        #pragma unroll
        for (int p = 0; p < 4; ++p) acc2[a][p] = (f32x4)0.f;

    for (int h = 0; h < 2; ++h) {
        __syncthreads();
        // L1: wave w computes global o-tiles h*16 + {2w, 2w+1}
        f32x4 accL[2][4];
        #pragma unroll
        for (int a = 0; a < 2; ++a)
            #pragma unroll
            for (int p = 0; p < 4; ++p) accL[a][p] = (f32x4)0.f;
        {
            bf16x8 a0 = w1f[(h*16 + 2*w    )*64 + lane];
            bf16x8 a1 = w1f[(h*16 + 2*w + 1)*64 + lane];
            __builtin_amdgcn_s_setprio(1);
            #pragma unroll
            for (int pt = 0; pt < 4; ++pt) {
                accL[0][pt] = __builtin_amdgcn_mfma_f32_16x16x32_bf16(a0, bfr[pt], accL[0][pt], 0, 0, 0);
                accL[1][pt] = __builtin_amdgcn_mfma_f32_16x16x32_bf16(a1, bfr[pt], accL[1][pt], 0, 0, 0);
            }
            __builtin_amdgcn_s_setprio(0);
        }
        // epilogue: relu -> bufA (local channels (2w+a)*16 + kg*4 .. +3)
        #pragma unroll
        for (int a = 0; a < 2; ++a) {
            int o0 = (2*w + a)*16 + kg*4;
            #pragma unroll
            for (int pt = 0; pt < 4; ++pt) {
                f32x4 d = accL[a][pt];
                int p = pt*16 + lp;
                uint2 q;
                q.x = (unsigned int)f2bf(fmaxf(d.x, 0.f)) |
                      ((unsigned int)f2bf(fmaxf(d.y, 0.f)) << 16);
                q.y = (unsigned int)f2bf(fmaxf(d.z, 0.f)) |
                      ((unsigned int)f2bf(fmaxf(d.w, 0.f)) << 16);
                *reinterpret_cast<uint2*>(&bufA[((o0 >> 3)*64 + p)*8 + (o0 & 7)]) = q;
            }
        }
        __syncthreads();
        // L2 accumulate over this half's 256 k-channels
        for (int ks = 0; ks < 8; ++ks) {
            int ksg = h*8 + ks;
            bf16x8 a0 = w2f[((2*w  )*16 + ksg)*64 + lane];
            bf16x8 a1 = w2f[((2*w+1)*16 + ksg)*64 + lane];
            __builtin_amdgcn_s_setprio(1);
            #pragma unroll
            for (int pt = 0; pt < 4; ++pt) {
                bf16x8 b = pA[(ks*4 + kg)*64 + pt*16 + lp];
                acc2[0][pt] = __builtin_amdgcn_mfma_f32_16x16x32_bf16(a0, b, acc2[0][pt], 0, 0, 0);
                acc2[1][pt] = __builtin_amdgcn_mfma_f32_16x16x32_bf16(a1, b, acc2[1][pt], 0, 0, 0);
            }
            __builtin_amdgcn_s_setprio(0);
        }
    }
    #pragma unroll
    for (int a = 0; a < 2; ++a) {
        int ot = 2*w + a;
        float4 bv = *reinterpret_cast<const float4*>(b2 + ot*16 + kg*4);
        int o0 = ot*16 + kg*4;
        #pragma unroll
        for (int pt = 0; pt < 4; ++pt) {
            f32x4 d = acc2[a][pt];
            int p = pt*16 + lp;
            uint2 q;
            q.x = (unsigned int)f2bf(fmaxf(d.x + bv.x, 0.f)) |
                  ((unsigned int)f2bf(fmaxf(d.y + bv.y, 0.f)) << 16);
            q.y = (unsigned int)f2bf(fmaxf(d.z + bv.z, 0.f)) |
                  ((unsigned int)f2bf(fmaxf(d.w + bv.w, 0.f)) << 16);
            *reinterpret_cast<uint2*>(&bufB[((o0 >> 3)*64 + p)*8 + (o0 & 7)]) = q;
        }
    }
    __syncthreads();

    // ---- L3 (256 -> 256): read bufB, write bufA ----
    f32x4 acc3[2][4];
    #pragma unroll
    for (int a = 0; a < 2; ++a)
        #pragma unroll
        for (int p = 0; p < 4; ++p) acc3[a][p] = (f32x4)0.f;
    for (int ks = 0; ks < 8; ++ks) {
        bf16x8 a0 = w3f[((2*w  )*8 + ks)*64 + lane];
        bf16x8 a1 = w3f[((2*w+1)*8 + ks)*64 + lane];
        __builtin_amdgcn_s_setprio(1);
        #pragma unroll
        for (int pt = 0; pt < 4; ++pt) {
            bf16x8 b = pB[(ks*4 + kg)*64 + pt*16 + lp];
            acc3[0][pt] = __builtin_amdgcn_mfma_f32_16x16x32_bf16(a0, b, acc3[0][pt], 0, 0, 0);
            acc3[1][pt] = __builtin_amdgcn_mfma_f32_16x16x32_bf16(a1, b, acc3[1][pt], 0, 0, 0);
        }
        __builtin_amdgcn_s_setprio(0);
    }
    #pragma unroll
    for (int a = 0; a < 2; ++a) {
        int ot = 2*w + a;
        float4 bv = *reinterpret_cast<const float4*>(b3 + ot*16 + kg*4);
        int o0 = ot*16 + kg*4;
        #pragma unroll
        for (int pt = 0; pt < 4; ++pt) {
            f32x4 d = acc3[a][pt];
            int p = pt*16 + lp;
            uint2 q;
            q.x = (unsigned int)f2bf(fmaxf(d.x + bv.x, 0.f)) |
                  ((unsigned int)f2bf(fmaxf(d.y + bv.y, 0.f)) << 16);
            q.y = (unsigned int)f2bf(fmaxf(d.z + bv.z, 0.f)) |
                  ((unsigned int)f2bf(fmaxf(d.w + bv.w, 0.f)) << 16);
            *reinterpret_cast<uint2*>(&bufA[((o0 >> 3)*64 + p)*8 + (o0 & 7)]) = q;
        }
    }
    __syncthreads();

    // ---- L4 (256 -> 128): read bufA, write bufB. wave w owns o-tile w. ----
    f32x4 acc4[4];
    #pragma unroll
    for (int p = 0; p < 4; ++p) acc4[p] = (f32x4)0.f;
    for (int ks = 0; ks < 8; ++ks) {
        bf16x8 a0 = w4f[(w*8 + ks)*64 + lane];
        __builtin_amdgcn_s_setprio(1);
        #pragma unroll
        for (int pt = 0; pt < 4; ++pt) {
            bf16x8 b = pA[(ks*4 + kg)*64 + pt*16 + lp];
            acc4[pt] = __builtin_amdgcn_mfma_f32_16x16x32_bf16(a0, b, acc4[pt], 0, 0, 0);
        }
        __builtin_amdgcn_s_setprio(0);
    }
    {
        int ot = w;
        float4 bv = *reinterpret_cast<const float4*>(b4 + ot*16 + kg*4);
        int o0 = ot*16 + kg*4;
        #pragma unroll
        for (int pt = 0; pt < 4; ++pt) {
            f32x4 d = acc4[pt];
            int p = pt*16 + lp;
            uint2 q;
            q.x = (unsigned int)f2bf(fmaxf(d.x + bv.x, 0.f)) |
                  ((unsigned int)f2bf(fmaxf(d.y + bv.y, 0.f)) << 16);
            q.y = (unsigned int)f2bf(fmaxf(d.z + bv.z, 0.f)) |
                  ((unsigned int)f2bf(fmaxf(d.w + bv.w, 0.f)) << 16);
            *reinterpret_cast<uint2*>(&bufB[((o0 >> 3)*64 + p)*8 + (o0 & 7)]) = q;
        }
    }
    __syncthreads();

    // ---- heads: MFMA on h4 (waves 0-3, pt=w), s1-dot fp32 (wave 4) ----
    f32x4 acch = (f32x4)0.f;
    if (w < 4) {
        for (int ks = 0; ks < 4; ++ks) {
            bf16x8 a0 = hpf[ks*64 + lane];
            bf16x8 b  = pB[(ks*4 + kg)*64 + w*16 + lp];
            acch = __builtin_amdgcn_mfma_f32_16x16x32_bf16(a0, b, acch, 0, 0, 0);
        }
    } else if (w == 4) {
        float part[10];
        #pragma unroll
        for (int c = 0; c < 10; ++c) part[c] = 0.f;
        const float* sf = s1 + bn * 256;
        #pragma unroll
        for (int t = 0; t < 4; ++t) {
            int k = lane + t*64;
            float sv = sf[k];
            #pragma unroll
            for (int c = 0; c < 8; ++c) part[c] = fmaf(regw[c*384 + k], sv, part[c]);
            part[8] = fmaf(clsw[k],       sv, part[8]);
            part[9] = fmaf(clsw[384 + k], sv, part[9]);
        }
        #pragma unroll
        for (int c = 0; c < 10; ++c) {
            float v = part[c];
            #pragma unroll
            for (int o2 = 1; o2 < 64; o2 <<= 1) v += __shfl_xor(v, o2, 64);
            if (lane == 0) sdot[c] = v;
        }
    }
    __syncthreads();

    // ---- dc contraction over the 64 slots ----
    if (w < 4) {
        int p = w*16 + lp;
        #pragma unroll
        for (int r = 0; r < 4; ++r) {
            int c = kg*4 + r;
            float v = 0.f;
            if (c < 10) {
                float hdot = acch[r] + sdot[c];
                float dw, hb;
                if (c < 8) { dw = dcrw[c*64 + p];     hb = regb[c];   }
                else       { dw = dccw[(c-8)*64 + p]; hb = clsb[c-8]; }
                v = (hdot + hb) * dw;
            }
            #pragma unroll
            for (int o2 = 1; o2 < 16; o2 <<= 1) v += __shfl_xor(v, o2, 64);
            if (lp == 0) pdc[w][c] = v;
        }
    }
    __syncthreads();
    if (tid < 16) {
        int c = tid;
        if (c < 10) {
            float s = pdc[0][c] + pdc[1][c] + pdc[2][c] + pdc[3][c];
            if (c < 8) outp[2048 + bn*8 + c] = s + dcrb[c];
            else       outp[bn*2 + (c-8)]    = s + dccb[c-8];
        }
    }
}

extern "C" void kernel_launch(void* const* d_in, const int* in_sizes, int n_in,
                              void* d_out, int out_size, void* d_ws, size_t ws_size,
                              hipStream_t stream)
{
    const float* grasp = (const float*)d_in[0];
    const float* pc    = (const float*)d_in[1];
    const float* s1    = (const float*)d_in[3];
    const float* W1 = (const float*)d_in[4];  const float* b1 = (const float*)d_in[5];
    const float* W2 = (const float*)d_in[6];  const float* b2 = (const float*)d_in[7];
    const float* W3 = (const float*)d_in[8];  const float* b3 = (const float*)d_in[9];
    const float* W4 = (const float*)d_in[10]; const float* b4 = (const float*)d_in[11];
    const float* regw = (const float*)d_in[12]; const float* regb = (const float*)d_in[13];
    const float* clsw = (const float*)d_in[14]; const float* clsb = (const float*)d_in[15];
    const float* dcrw = (const float*)d_in[16]; const float* dcrb = (const float*)d_in[17];
    const float* dccw = (const float*)d_in[18]; const float* dccb = (const float*)d_in[19];
    float* outp = (float*)d_out;
    // out layout: x_cls [0,2048) | x_reg [2048,10240) | mask [10240,11264)

    char* ws = (char*)d_ws;
    unsigned short* W2p = (unsigned short*)ws;                // 262144 B
    unsigned short* W3p = (unsigned short*)(ws + 262144);     // 131072 B
    unsigned short* W4p = (unsigned short*)(ws + 393216);     //  65536 B
    unsigned short* Hp  = (unsigned short*)(ws + 458752);     //   4096 B
    unsigned short* W1p = (unsigned short*)(ws + 462848);     //  32768 B
    float4*        xyzw = (float4*)       (ws + 495616);      // 640000 B

    k_pack<<<453, 256, 0, stream>>>(W1, b1, W2, W3, W4, regw, clsw, pc,
                                    W2p, W3p, W4p, Hp, W1p, xyzw);
    k_fused<<<1024, 512, 0, stream>>>(grasp, xyzw, s1, b2, b3, b4,
                                      W2p, W3p, W4p, Hp, W1p,
                                      regw, regb, clsw, clsb, dcrw, dcrb, dccw, dccb,
                                      outp);
}